// Round 4
// baseline (479.107 us; speedup 1.0000x reference)
//
#include <hip/hip_runtime.h>

// FeatureVolume: left/right [B=2, H=256, W=256, C=16] f32
// out [B, 2D=48, H, W, 2C=32] f32, disp = d-24, src_w = w - disp = w - d + 24
// out[b,d,h,w, 0:16] = valid ? left [b,h,w,:]   : 0
// out[b,d,h,w,16:32] = valid ? right[b,h,src_w,:] : 0,  valid = 0<=src_w<W
//
// One block per (b,h), 1024 threads. Thread owns fixed (wlo = t>>3, c4 = t&7)
// and covers w in {wlo, wlo+128}. Left value is CONSTANT across d -> held in
// registers (loaded once from global; left never touches LDS). Right row
// staged once in LDS (16 KB). d-loop unrolled x4: 8 independent ds_reads
// issued, then 8 lane-contiguous full-line stores (1 KB/wave each).

#define MAXD 24
#define ND   48
#define HH   256
#define WW   256
#define SLICE 524288u   // HH*WW*8 float4 per (b,d) slice

__global__ __launch_bounds__(1024) void FeatureVolume_68762426409246_kernel(
    const float4* __restrict__ left,
    const float4* __restrict__ right,
    float4* __restrict__ out) {
    __shared__ float4 rlds[WW * 4];   // right row: 1024 float4 = 16 KB

    const unsigned int bh  = blockIdx.x;     // b*HH + h
    const unsigned int b   = bh >> 8;
    const unsigned int t   = threadIdx.x;    // 0..1023
    const unsigned int c4  = t & 7u;         // out-row float4 slot
    const unsigned int wlo = t >> 3;         // 0..127
    const unsigned int row = bh << 10;       // row base in float4 (W*C/4 = 1024)

    // stage right row: one float4 per thread, coalesced
    rlds[t] = right[row + t];

    // left values for this thread's two w slots (meaningful for c4<4 lanes;
    // c4>=4 lanes load a harmless in-range value they never use)
    const unsigned int lbase = row + (wlo << 2) + (c4 & 3u);
    const float4 L0 = left[lbase];           // w = wlo
    const float4 L1 = left[lbase + 512u];    // w = wlo + 128
    __syncthreads();

    const bool   isL = (c4 < 4u);
    const float4 Z   = make_float4(0.f, 0.f, 0.f, 0.f);

    // out f4 index of (b, d=0, h, wlo, c4):  ((b*ND*HH + h) * 2048) + t
    float4* o0 = out + (((unsigned long long)(b * ND * HH + (bh & 255u))) << 11) + t;

    for (int d = 0; d < ND; d += 4) {
        float4 v[4][2];
        #pragma unroll
        for (int k = 0; k < 4; ++k) {
            const int s0 = (int)wlo + MAXD - (d + k);   // src col for wseg 0
            const int s1 = s0 + 128;                    // src col for wseg 1
            const int c0 = min(max(s0, 0), WW - 1);
            const int c1 = min(max(s1, 0), WW - 1);
            const float4 r0 = rlds[(c0 << 2) + (int)(c4 & 3u)];
            const float4 r1 = rlds[(c1 << 2) + (int)(c4 & 3u)];
            const float4 a0 = isL ? L0 : r0;
            const float4 a1 = isL ? L1 : r1;
            v[k][0] = ((unsigned)s0 < (unsigned)WW) ? a0 : Z;
            v[k][1] = ((unsigned)s1 < (unsigned)WW) ? a1 : Z;
        }
        #pragma unroll
        for (int k = 0; k < 4; ++k) {
            float4* p = o0 + (unsigned)(d + k) * SLICE;
            p[0]    = v[k][0];   // wseg 0: 16 KB sweep, lane-contiguous
            p[1024] = v[k][1];   // wseg 1: next 16 KB of same d-slice
        }
    }
}

extern "C" void kernel_launch(void* const* d_in, const int* in_sizes, int n_in,
                              void* d_out, int out_size, void* d_ws, size_t ws_size,
                              hipStream_t stream) {
    const float4* left  = (const float4*)d_in[0];
    const float4* right = (const float4*)d_in[1];
    float4* out = (float4*)d_out;

    // one block per (b,h): 512 blocks x 1024 threads
    FeatureVolume_68762426409246_kernel<<<2 * HH, 1024, 0, stream>>>(
        left, right, out);
}

// Round 5
// 363.624 us; speedup vs baseline: 1.3176x; 1.3176x over previous
//
#include <hip/hip_runtime.h>

// FeatureVolume: left/right [B=2, H=256, W=256, C=16] f32
// out [B, 2D=48, H, W, 2C=32] f32, disp = d-24, s = w - d + 24
// out[b,d,h,w, 0:16] = (0<=s<W) ? left [b,h,w,:] : 0
// out[b,d,h,w,16:32] = (0<=s<W) ? right[b,h,s,:] : 0
//
// R5: block = (b, d, h-chunk). Each block writes ONE sequential 512 KB span
// (16 h-rows of a (b,d) slice) -- single forward-marching write stream per
// block (R3/R4 lesson: fragmented or half-line store streams tank HBM BW).
// Row pair (left,right) double-buffered through LDS; one barrier per row.
// Inputs are L2/L3-resident (16 MB total; same-row blocks share an XCD).

#define MAXD 24
#define ND   48
#define HH   256
#define WW   256
#define HC   16                      // h rows per block
#define ROW_F4 1024                  // (W*C)/4 float4 per input row
#define OUT_ROW_F4 2048              // (W*2C)/4 float4 per output row
#define SLICE_F4 (HH * OUT_ROW_F4)   // float4 per (b,d) slice = 524288

__global__ __launch_bounds__(1024) void FeatureVolume_68762426409246_kernel(
    const float4* __restrict__ left,
    const float4* __restrict__ right,
    float4* __restrict__ out) {
    __shared__ float4 buf[2][2 * ROW_F4];   // [pingpong][ left | right ] 64 KB

    const unsigned bid = blockIdx.x;
    const unsigned hc  = bid & 15u;
    const unsigned bd  = bid >> 4;          // b*ND + d
    const unsigned b   = (bd >= ND) ? 1u : 0u;
    const unsigned d   = bd - b * ND;
    const unsigned t   = threadIdx.x;       // 0..1023

    const unsigned h0 = hc * HC;
    const float4* lrow = left  + (size_t)(b * HH + h0) * ROW_F4;
    const float4* rrow = right + (size_t)(b * HH + h0) * ROW_F4;

    // prologue: stage row h0 into buf[0] (coalesced, 1 float4/thread/side)
    {
        float4 lv = lrow[t];
        float4 rv = rrow[t];
        buf[0][t]          = lv;
        buf[0][ROW_F4 + t] = rv;
    }
    __syncthreads();

    // fixed per-thread output slots: (w, c4) and (w+128, c4)
    const unsigned c4 = t & 7u;
    const unsigned w  = t >> 3;                       // 0..127
    const bool isL = (c4 < 4u);
    const int s0 = (int)w + MAXD - (int)d;            // right src col, wseg0
    const int s1 = s0 + 128;                          // wseg1
    const bool val0 = ((unsigned)s0 < (unsigned)WW);
    const bool val1 = ((unsigned)s1 < (unsigned)WW);
    const unsigned cr0 = (unsigned)min(max(s0, 0), WW - 1);
    const unsigned cr1 = (unsigned)min(max(s1, 0), WW - 1);
    const unsigned a0 = isL ? (w * 4u + c4)
                            : (ROW_F4 + cr0 * 4u + (c4 - 4u));
    const unsigned a1 = isL ? ((w + 128u) * 4u + c4)
                            : (ROW_F4 + cr1 * 4u + (c4 - 4u));
    const float4 Z = make_float4(0.f, 0.f, 0.f, 0.f);

    // sequential write cursor: (b,d) slice + h0 row
    float4* op = out + (size_t)bd * SLICE_F4 + (size_t)h0 * OUT_ROW_F4 + t;

    unsigned pp = 0;
    for (int i = 0; i < HC; ++i) {
        float4 lv, rv;
        const bool more = (i + 1 < HC);
        if (more) {                       // issue next-row loads early
            lv = lrow[(size_t)(i + 1) * ROW_F4 + t];
            rv = rrow[(size_t)(i + 1) * ROW_F4 + t];
        }
        // serve current row from LDS, store full-line contiguous bursts
        float4 x0 = buf[pp][a0];
        float4 x1 = buf[pp][a1];
        op[0]    = val0 ? x0 : Z;         // w 0..127   (16 KB burst)
        op[1024] = val1 ? x1 : Z;         // w 128..255 (next 16 KB)
        if (more) {                       // write next row into other buffer
            buf[pp ^ 1][t]          = lv;
            buf[pp ^ 1][ROW_F4 + t] = rv;
        }
        __syncthreads();
        pp ^= 1;
        op += OUT_ROW_F4;
    }
}

extern "C" void kernel_launch(void* const* d_in, const int* in_sizes, int n_in,
                              void* d_out, int out_size, void* d_ws, size_t ws_size,
                              hipStream_t stream) {
    const float4* left  = (const float4*)d_in[0];
    const float4* right = (const float4*)d_in[1];
    float4* out = (float4*)d_out;

    // grid = B*ND*(HH/HC) = 2*48*16 = 1536 blocks x 1024 threads
    FeatureVolume_68762426409246_kernel<<<2 * ND * (HH / HC), 1024, 0, stream>>>(
        left, right, out);
}

// Round 6
// 150.361 us; speedup vs baseline: 3.1864x; 2.4183x over previous
//
#include <hip/hip_runtime.h>

// FeatureVolume: left/right [B=2, H=256, W=256, C=16] f32
// out [B, 2D=48, H, W, 2C=32] f32, s = w - d + 24
// out[b,d,h,w, 0:16] = (0<=s<W) ? left [b,h,w,:] : 0
// out[b,d,h,w,16:32] = (0<=s<W) ? right[b,h,s,:] : 0
//
// R6: R2's store pattern (512 blocks=(b,h), marching 16KB wave-contiguous
// bursts, ONE barrier) with the serialization removed:
//  - left values in registers (constant across d)
//  - right row in ZERO-PADDED LDS (cols -24..279) -> right-half boundary
//    masking is free (OOB reads hit pre-zeroed pad)
//  - LDS cursors decrement 64B/d; software-pipelined next-d prefetch
//  - left-half validity: two compares (d<=wlo+24 for wseg0, d>=wlo-103 for wseg1)

#define MAXD 24
#define ND   48
#define HH   256
#define WW   256
#define SLICE_F4 (HH * WW * 8)   // 524288 float4 per (b,d) slice

__global__ __launch_bounds__(1024, 8) void FeatureVolume_68762426409246_kernel(
    const float4* __restrict__ left,
    const float4* __restrict__ right,
    float4* __restrict__ out) {
    // padded right row: cols -24..279 -> 304 cols x 4 float4 = 1216 f4 (19.5 KB)
    __shared__ float4 rpad[1216];

    const unsigned bh  = blockIdx.x;      // b*HH + h
    const unsigned b   = bh >> 8;
    const unsigned t   = threadIdx.x;     // 0..1023
    const unsigned c4  = t & 7u;          // out-row float4 slot
    const unsigned cc  = t & 3u;          // channel quad within a pixel
    const unsigned wlo = t >> 3;          // 0..127
    const unsigned row = bh << 10;        // input row base (1024 f4/row)
    const float4 Z = make_float4(0.f, 0.f, 0.f, 0.f);

    // zero the pads, stage right row (col s lives at f4 index (24+s)*4+cc)
    if (t < 96u)            rpad[t] = Z;            // cols -24..-1
    else if (t < 192u)      rpad[1024u + t] = Z;    // cols 256..279 (1120..1215)
    rpad[96u + t] = right[row + t];                 // cols 0..255

    // left values for this thread's two w slots (c4>=4 lanes: unused)
    const float4 L0 = left[row + (wlo << 2) + cc];          // w = wlo
    const float4 L1 = left[row + ((wlo + 128u) << 2) + cc]; // w = wlo+128
    __syncthreads();

    const bool isL   = (c4 < 4u);
    const int  dmax0 = (int)wlo + MAXD;         // wseg0 left valid iff d <= dmax0
    const int  dmin1 = (int)wlo - 103;          // wseg1 left valid iff d >= dmin1

    // LDS cursors for right src col s(d) = wlo+24-d (plus +24 pad offset)
    unsigned a0 = (48u + wlo) * 4u + cc;        // d=0, wseg0
    unsigned a1 = a0 + 512u;                    // d=0, wseg1 (s+128)

    // store cursor: f4 index of (b, d=0, h, wlo, c4) = base + t
    float4* op = out + (((size_t)(b * (ND * HH) + (bh & 255u))) << 11) + t;

    float4 r0 = rpad[a0];
    float4 r1 = rpad[a1];
    #pragma unroll 4
    for (int d = 0; d < ND - 1; ++d) {
        a0 -= 4u; a1 -= 4u;
        float4 n0 = rpad[a0];                   // prefetch d+1
        float4 n1 = rpad[a1];
        float4 x0 = isL ? ((d <= dmax0) ? L0 : Z) : r0;
        float4 x1 = isL ? ((d >= dmin1) ? L1 : Z) : r1;
        op[0]    = x0;                          // w = wlo       (16 KB burst)
        op[1024] = x1;                          // w = wlo + 128 (next 16 KB)
        op += SLICE_F4;
        r0 = n0; r1 = n1;
    }
    {   // epilogue d = ND-1 (no prefetch)
        const int d = ND - 1;
        float4 x0 = isL ? ((d <= dmax0) ? L0 : Z) : r0;
        float4 x1 = isL ? ((d >= dmin1) ? L1 : Z) : r1;
        op[0]    = x0;
        op[1024] = x1;
    }
}

extern "C" void kernel_launch(void* const* d_in, const int* in_sizes, int n_in,
                              void* d_out, int out_size, void* d_ws, size_t ws_size,
                              hipStream_t stream) {
    const float4* left  = (const float4*)d_in[0];
    const float4* right = (const float4*)d_in[1];
    float4* out = (float4*)d_out;

    // one block per (b,h): 512 blocks x 1024 threads
    FeatureVolume_68762426409246_kernel<<<2 * HH, 1024, 0, stream>>>(
        left, right, out);
}